// Round 12
// baseline (16610.245 us; speedup 1.0000x reference)
//
#include <hip/hip_runtime.h>

#define NN 32768
#define NE 32752
#define P0 16384
#define NLEV 12
#define NBLK 512

__constant__ int d_starts[NLEV + 1] = {0, 16384, 24576, 28672, 30720, 31744,
                                       32256, 32512, 32640, 32704, 32736, 32752, 32768};

typedef __attribute__((ext_vector_type(8))) short short8;  // 8 bf16
typedef __attribute__((ext_vector_type(4))) float f32x4;   // MFMA C/D
typedef unsigned short u16;

__device__ __forceinline__ float sigm(float x) { return 1.0f / (1.0f + __expf(-x)); }
__device__ __forceinline__ float tanh_fast(float x) { return 2.0f / (1.0f + __expf(-2.0f * x)) - 1.0f; }
__device__ __forceinline__ u16 bfr(float f) {
  unsigned int u = __float_as_uint(f);
  return (u16)((u + 0x7FFFu + ((u >> 16) & 1u)) >> 16);
}
__device__ __forceinline__ float bflo(float f, u16 hi) {
  return f - __uint_as_float((unsigned int)hi << 16);
}

__device__ __forceinline__ void gload16(const u16* g, u16* l) {
  __builtin_amdgcn_global_load_lds((const __attribute__((address_space(1))) unsigned int*)(const void*)g,
                                   (__attribute__((address_space(3))) unsigned int*)(void*)l, 16, 0, 0);
}

// Swizzled fragment read: logical slot sb of row lives at slot sb^(row&7).
__device__ __forceinline__ short8 fragld(const u16* s, int row, int sb) {
  return *reinterpret_cast<const short8*>(s + row * 64 + ((sb ^ (row & 7)) << 3));
}
#define MFMA(ACC, A, B) ACC = __builtin_amdgcn_mfma_f32_16x16x32_bf16(A, B, ACC, 0, 0, 0)

// Device-wide barrier: atomic arrive + generation spin. __threadfence (device
// scope) on both sides for cross-XCD visibility of normal loads/stores.
__device__ __forceinline__ void gbar(int* cnt, int* gen) {
  __syncthreads();
  if (threadIdx.x == 0) {
    __threadfence();
    int g = __hip_atomic_load(gen, __ATOMIC_RELAXED, __HIP_MEMORY_SCOPE_AGENT);
    int v = __hip_atomic_fetch_add(cnt, 1, __ATOMIC_ACQ_REL, __HIP_MEMORY_SCOPE_AGENT);
    if (v == NBLK - 1) {
      __hip_atomic_store(cnt, 0, __ATOMIC_RELAXED, __HIP_MEMORY_SCOPE_AGENT);
      __hip_atomic_store(gen, g + 1, __ATOMIC_RELEASE, __HIP_MEMORY_SCOPE_AGENT);
    } else {
      while (__hip_atomic_load(gen, __ATOMIC_ACQUIRE, __HIP_MEMORY_SCOPE_AGENT) == g)
        __builtin_amdgcn_s_sleep(2);
    }
    __threadfence();
  }
  __syncthreads();
}

// ---------------------------------------------------------------------------
// split_all: fp32 -> bf16 hi/lo planes for all 5 tensors + zero counts/bar.
// ---------------------------------------------------------------------------
__global__ __launch_bounds__(256) void split_all(
    const float* __restrict__ f, const float* __restrict__ wio, const float* __restrict__ uio,
    const float* __restrict__ wf, const float* __restrict__ uf,
    u16* __restrict__ PFh, u16* __restrict__ PFl, u16* __restrict__ Wih, u16* __restrict__ Wil,
    u16* __restrict__ Uih, u16* __restrict__ Uil, u16* __restrict__ Wfh, u16* __restrict__ Wfl,
    u16* __restrict__ Ufh, u16* __restrict__ Ufl, int* __restrict__ zbase) {
  const int NF4 = 2097152, NW4 = 49152, NS4 = 16384, NZ = 16386;
  const int total = NF4 + 2 * NW4 + 2 * NS4 + NZ;
  int i = blockIdx.x * 256 + threadIdx.x;
  const int stride = gridDim.x * 256;
  for (; i < total; i += stride) {
    int j = i;
    const float* s;
    u16 *h, *l;
    if (j < NF4) { s = f; h = PFh; l = PFl; }
    else {
      j -= NF4;
      if (j < NW4) { s = wio; h = Wih; l = Wil; }
      else {
        j -= NW4;
        if (j < NW4) { s = uio; h = Uih; l = Uil; }
        else {
          j -= NW4;
          if (j < NS4) { s = wf; h = Wfh; l = Wfl; }
          else {
            j -= NS4;
            if (j < NS4) { s = uf; h = Ufh; l = Ufl; }
            else { zbase[j - NS4] = 0; continue; }
          }
        }
      }
    }
    const float4 v = reinterpret_cast<const float4*>(s)[j];
    u16 hx = bfr(v.x), hy = bfr(v.y), hz = bfr(v.z), hw = bfr(v.w);
    reinterpret_cast<ushort4*>(h)[j] = make_ushort4(hx, hy, hz, hw);
    reinterpret_cast<ushort4*>(l)[j] = make_ushort4(bfr(bflo(v.x, hx)), bfr(bflo(v.y, hy)),
                                                    bfr(bflo(v.z, hz)), bfr(bflo(v.w, hw)));
  }
}

// ---------------------------------------------------------------------------
// act3 tile: 64x64x3gates, double-buffered 1-sync K-loop.
// ---------------------------------------------------------------------------
template <bool LEAF>
__device__ void act3_tile(
    int tile, int M, int row0,
    const u16* AFh, const u16* AFl, const u16* HSh, const u16* HSl,
    const u16* Wh, const u16* Wl, const u16* Uh, const u16* Ul,
    const float* bias, const float* c_part,
    float* h_d, float* c_d, u16* HWh, u16* HWl, u16* lds) {
  const int tid = threadIdx.x, lane = tid & 63;
  const int w = tid >> 6, wr = w >> 1, wc = w & 1;
  const int l16 = lane & 15, lhi = lane >> 4;
  const int rb = (tile >> 2) * 64, cb = (tile & 3) * 64;
  const int cr = lane >> 3, sl = lane & 7;
  u16 *As0 = lds, *As1 = lds + 4096, *Bs0 = lds + 8192, *Bs1 = lds + 20480;
  f32x4 acc[3][2][2] = {};
  const int t0 = LEAF ? 12 : 0;

  auto stage = [&](int t, u16* Ad, u16* Bd) {
    const int sp = (t % 12) >> 2;
    const int k0 = (t & 3) << 6;
    const bool wph = (t >= 12);
#pragma unroll
    for (int i = 0; i < 2; ++i) {
      const int ch = (w << 1) + i;
      const int r = (ch << 3) + cr;
      int rr = rb + r; if (rr >= M) rr = M - 1;
      const u16* base = wph ? ((sp == 1) ? AFl : AFh) : ((sp == 1) ? HSl : HSh);
      gload16(base + (size_t)rr * 256 + k0 + ((sl ^ (r & 7)) << 3), &Ad[ch * 512]);
    }
#pragma unroll
    for (int i = 0; i < 6; ++i) {
      const int ch = w * 6 + i;
      const int g = ch >> 3;
      const int rl = ((ch & 7) << 3) + cr;
      const u16* base = wph ? ((sp == 2) ? Wl : Wh) : ((sp == 2) ? Ul : Uh);
      gload16(base + (size_t)(g * 256 + cb + rl) * 256 + k0 + ((sl ^ (rl & 7)) << 3), &Bd[ch * 512]);
    }
  };

  stage(t0, As0, Bs0);
  __syncthreads();  // implicit vmcnt drain: buf0 ready
  for (int t = t0; t < 24; ++t) {
    const int cur = (t - t0) & 1;
    if (t + 1 < 24) stage(t + 1, cur ? As0 : As1, cur ? Bs0 : Bs1);  // async, overlaps MFMA
    const u16* Ac = cur ? As1 : As0;
    const u16* Bc = cur ? Bs1 : Bs0;
#pragma unroll
    for (int ks = 0; ks < 2; ++ks) {
      const int sb = (ks << 2) + lhi;
      const short8 a0 = fragld(Ac, wr * 32 + l16, sb);
      const short8 a1 = fragld(Ac, wr * 32 + 16 + l16, sb);
#pragma unroll
      for (int g = 0; g < 3; ++g) {
        const u16* bg = Bc + g * 4096;
        const short8 b0 = fragld(bg, wc * 32 + l16, sb);
        const short8 b1 = fragld(bg, wc * 32 + 16 + l16, sb);
        MFMA(acc[g][0][0], a0, b0);
        MFMA(acc[g][0][1], a0, b1);
        MFMA(acc[g][1][0], a1, b0);
        MFMA(acc[g][1][1], a1, b1);
      }
    }
    __syncthreads();  // drains stage(t+1) DMA + all reads of current buf done
  }

#pragma unroll
  for (int mi = 0; mi < 2; ++mi)
#pragma unroll
    for (int q = 0; q < 4; ++q) {
      const int lrow = rb + wr * 32 + mi * 16 + lhi * 4 + q;
      if (lrow >= M) continue;
      const size_t grow = (size_t)(row0 + lrow);
#pragma unroll
      for (int ni = 0; ni < 2; ++ni) {
        const int col = cb + wc * 32 + ni * 16 + l16;
        const float iv = acc[0][mi][ni][q] + bias[col];
        const float ov = acc[1][mi][ni][q] + bias[256 + col];
        const float uv = acc[2][mi][ni][q] + bias[512 + col];
        float cc = sigm(iv) * tanh_fast(uv);
        if (!LEAF) cc += c_part[(size_t)lrow * 256 + col];
        const float hh = sigm(ov) * tanh_fast(cc);
        h_d[grow * 256 + col] = hh;
        c_d[grow * 256 + col] = cc;
        const u16 hb = bfr(hh);
        HWh[(size_t)lrow * 256 + col] = hb;
        HWl[(size_t)lrow * 256 + col] = bfr(bflo(hh, hb));
      }
    }
}

// ---------------------------------------------------------------------------
// edge tile: 128x64, double-buffered 1-sync K-loop.
// ---------------------------------------------------------------------------
__device__ void edge_tile(
    int tile, int M, int e0,
    const u16* AUh, const u16* AUl, const u16* PFh, const u16* PFl,
    const u16* Ufh, const u16* Ufl, const u16* Wfh, const u16* Wfl,
    const float* Wfb, const int* parent, const float* c_d, float* fc,
    u16* lds, int* pars) {
  const int tid = threadIdx.x, lane = tid & 63;
  const int w = tid >> 6, wr = w >> 1, wc = w & 1;
  const int l16 = lane & 15, lhi = lane >> 4;
  const int rb = (tile >> 2) * 128, cb = (tile & 3) * 64;
  const int cr = lane >> 3, sl = lane & 7;
  __syncthreads();  // protect pars against previous tile's epilogue readers
  if (tid < 128) {
    int r = rb + tid;
    if (r >= M) r = M - 1;
    pars[tid] = parent[e0 + r];
  }
  __syncthreads();
  u16 *As0 = lds, *As1 = lds + 8192, *Bs0 = lds + 16384, *Bs1 = lds + 20480;
  f32x4 acc[4][2] = {};

  auto stage = [&](int t, u16* Ad, u16* Bd) {
    const int sp = (t % 12) >> 2;
    const int k0 = (t & 3) << 6;
    const bool wph = (t >= 12);
#pragma unroll
    for (int i = 0; i < 4; ++i) {
      const int ch = (w << 2) + i;
      const int r = (ch << 3) + cr;
      const u16* base;
      size_t row;
      if (wph) { base = (sp == 1) ? PFl : PFh; row = (size_t)pars[r]; }
      else {
        base = (sp == 1) ? AUl : AUh;
        int rr = rb + r; if (rr >= M) rr = M - 1;
        row = (size_t)rr;
      }
      gload16(base + row * 256 + k0 + ((sl ^ (r & 7)) << 3), &Ad[ch * 512]);
    }
#pragma unroll
    for (int i = 0; i < 2; ++i) {
      const int ch = (w << 1) + i;
      const int r = (ch << 3) + cr;
      const u16* base = wph ? ((sp == 2) ? Wfl : Wfh) : ((sp == 2) ? Ufl : Ufh);
      gload16(base + (size_t)(cb + r) * 256 + k0 + ((sl ^ (r & 7)) << 3), &Bd[ch * 512]);
    }
  };

  stage(0, As0, Bs0);
  __syncthreads();
  for (int t = 0; t < 24; ++t) {
    const int cur = t & 1;
    if (t + 1 < 24) stage(t + 1, cur ? As0 : As1, cur ? Bs0 : Bs1);
    const u16* Ac = cur ? As1 : As0;
    const u16* Bc = cur ? Bs1 : Bs0;
#pragma unroll
    for (int ks = 0; ks < 2; ++ks) {
      const int sb = (ks << 2) + lhi;
      const short8 b0 = fragld(Bc, wc * 32 + l16, sb);
      const short8 b1 = fragld(Bc, wc * 32 + 16 + l16, sb);
#pragma unroll
      for (int mi = 0; mi < 4; ++mi) {
        const short8 a = fragld(Ac, wr * 64 + mi * 16 + l16, sb);
        MFMA(acc[mi][0], a, b0);
        MFMA(acc[mi][1], a, b1);
      }
    }
    __syncthreads();
  }

#pragma unroll
  for (int mi = 0; mi < 4; ++mi)
#pragma unroll
    for (int q = 0; q < 4; ++q) {
      const int row = rb + wr * 64 + mi * 16 + lhi * 4 + q;
      if (row >= M) continue;
      const int e = e0 + row;
#pragma unroll
      for (int ni = 0; ni < 2; ++ni) {
        const int col = cb + wc * 32 + ni * 16 + l16;
        const float f = sigm(acc[mi][ni][q] + Wfb[col]);
        fc[(size_t)row * 256 + col] = f * c_d[(size_t)e * 256 + col];
      }
    }
}

__device__ void prep_row(int b, const float* h_d, const float* fc,
                         const int* offs, const int* eidx,
                         u16* HSh, u16* HSl, float* c_part, int pl0, int e0) {
  const int col = threadIdx.x;
  const int p = pl0 + b;
  float hs = 0.f, cp = 0.f;
  const int j1 = offs[p + 1];
  for (int j = offs[p]; j < j1; ++j) {
    const int e = eidx[j];  // edge id == child node id (identity child_idx)
    hs += h_d[(size_t)e * 256 + col];
    cp += fc[(size_t)(e - e0) * 256 + col];
  }
  const u16 hh = bfr(hs);
  HSh[b * 256 + col] = hh;
  HSl[b * 256 + col] = bfr(bflo(hs, hh));
  c_part[b * 256 + col] = cp;
}

// ---------------------------------------------------------------------------
// Persistent kernel: CSR + leaf + levels 1..11 with device-wide barriers.
// 512 blocks x 256 threads, 2 blocks/CU guaranteed -> all co-resident.
// ---------------------------------------------------------------------------
__global__ __launch_bounds__(256, 2) void tree_levels(
    const int* __restrict__ parent,
    u16* __restrict__ PFh, u16* __restrict__ PFl,
    u16* __restrict__ H0h, u16* __restrict__ H0l,
    const u16* __restrict__ Wiouh, const u16* __restrict__ Wioul,
    const u16* __restrict__ Uiouh, const u16* __restrict__ Uioul,
    const u16* __restrict__ Wfh, const u16* __restrict__ Wfl,
    const u16* __restrict__ Ufh, const u16* __restrict__ Ufl,
    const float* __restrict__ Wioub, const float* __restrict__ Wfb,
    float* __restrict__ h_d, float* __restrict__ c_d,
    float* __restrict__ fc, float* __restrict__ c_part,
    u16* __restrict__ HSh, u16* __restrict__ HSl,
    int* __restrict__ counts, int* __restrict__ offs, int* __restrict__ cursor,
    int* __restrict__ eidx, int* __restrict__ barcnt, int* __restrict__ bargen) {
  __shared__ u16 lds[32768];  // 64KB: dbuf GEMM tiles
  __shared__ int pars[128];
  const int bid = blockIdx.x;
  const int tid = threadIdx.x;
  const int gid = bid * 256 + tid;

  // phase 0: CSR count + leaf act3 (features x W_iou)
  for (int e = gid; e < NE; e += NBLK * 256) atomicAdd(&counts[parent[e] - P0], 1);
  for (int tile = bid; tile < 1024; tile += NBLK)
    act3_tile<true>(tile, 16384, 0, PFh, PFl, nullptr, nullptr,
                    Wiouh, Wioul, nullptr, nullptr, Wioub, nullptr,
                    h_d, c_d, H0h, H0l, lds);
  gbar(barcnt, bargen);

  // phase 1: CSR scan (block 0 only)
  if (bid == 0) {
    int* ip = (int*)lds;
    const int base = tid * 64;
    int s = 0;
    for (int i = 0; i < 64; ++i) s += counts[base + i];
    ip[tid] = s;
    __syncthreads();
    for (int off = 1; off < 256; off <<= 1) {
      int v = (tid >= off) ? ip[tid - off] : 0;
      __syncthreads();
      ip[tid] += v;
      __syncthreads();
    }
    int excl = ip[tid] - s;
    for (int i = 0; i < 64; ++i) {
      const int c0 = counts[base + i];
      offs[base + i] = excl;
      cursor[base + i] = excl;
      excl += c0;
    }
    if (tid == 255) offs[16384] = excl;
  }
  gbar(barcnt, bargen);

  // phase 2: CSR fill rides with level-1 edge (prep L1 is bar-separated)
  for (int e = gid; e < NE; e += NBLK * 256) {
    const int pos = atomicAdd(&cursor[parent[e] - P0], 1);
    eidx[pos] = e;
  }

  for (int n = 1; n < NLEV; ++n) {
    const int e0 = d_starts[n - 1];
    const int Me = d_starts[n] - e0;
    const int r0 = d_starts[n];
    const int Mn = d_starts[n + 1] - r0;
    const u16* AUh = (n == 1) ? H0h : PFh + (size_t)(e0 - P0) * 256;
    const u16* AUl = (n == 1) ? H0l : PFl + (size_t)(e0 - P0) * 256;

    const int te = ((Me + 127) / 128) * 4;
    for (int tile = bid; tile < te; tile += NBLK)
      edge_tile(tile, Me, e0, AUh, AUl, PFh, PFl, Ufh, Ufl, Wfh, Wfl, Wfb,
                parent, c_d, fc, lds, pars);
    gbar(barcnt, bargen);

    for (int b = bid; b < Mn; b += NBLK)
      prep_row(b, h_d, fc, offs, eidx, HSh, HSl, c_part, r0 - P0, e0);
    gbar(barcnt, bargen);

    const int ta = ((Mn + 63) / 64) * 4;
    for (int tile = bid; tile < ta; tile += NBLK)
      act3_tile<false>(tile, Mn, r0,
                       PFh + (size_t)r0 * 256, PFl + (size_t)r0 * 256, HSh, HSl,
                       Wiouh, Wioul, Uiouh, Uioul, Wioub, c_part,
                       h_d, c_d, PFh + (size_t)(r0 - P0) * 256,
                       PFl + (size_t)(r0 - P0) * 256, lds);
    gbar(barcnt, bargen);
  }
}

extern "C" void kernel_launch(void* const* d_in, const int* in_sizes, int n_in,
                              void* d_out, int out_size, void* d_ws, size_t ws_size,
                              hipStream_t stream) {
  const float* features = (const float*)d_in[0];
  const float* W_iou_w = (const float*)d_in[1];
  const float* W_iou_b = (const float*)d_in[2];
  const float* U_iou_w = (const float*)d_in[3];
  const float* W_f_w = (const float*)d_in[4];
  const float* W_f_b = (const float*)d_in[5];
  const float* U_f_w = (const float*)d_in[6];
  const int* parent_idx = (const int*)d_in[9];

  float* h_d = (float*)d_out;
  float* c_d = h_d + (size_t)NN * 256;

  // Workspace carve (~86.5 MB). PF leaf rows [0,16384) are overwritten by
  // parent h-planes (node r>=16384 at PF row r-16384) after leaf phase.
  u16* PFh = (u16*)d_ws;
  u16* PFl = PFh + (size_t)NN * 256;
  u16* H0h = PFl + (size_t)NN * 256;
  u16* H0l = H0h + (size_t)P0 * 256;
  u16* Wiouh = H0l + (size_t)P0 * 256;
  u16* Wioul = Wiouh + 768 * 256;
  u16* Uiouh = Wioul + 768 * 256;
  u16* Uioul = Uiouh + 768 * 256;
  u16* Wfh = Uioul + 768 * 256;
  u16* Wfl = Wfh + 256 * 256;
  u16* Ufh = Wfl + 256 * 256;
  u16* Ufl = Ufh + 256 * 256;
  u16* HSh = Ufl + 256 * 256;
  u16* HSl = HSh + (size_t)8192 * 256;
  float* fc = (float*)(HSl + (size_t)8192 * 256);
  float* c_part = fc + (size_t)16384 * 256;
  int* counts = (int*)(c_part + (size_t)8192 * 256);  // 16384
  int* barcnt = counts + 16384;                       // barrier state,
  int* bargen = counts + 16385;                       // zeroed with counts
  int* offs = counts + 16386;                         // 16385 (+pad)
  int* cursor = offs + 16400;                         // 16384
  int* eidx = cursor + 16384;                         // 32752

  split_all<<<2048, 256, 0, stream>>>(features, W_iou_w, U_iou_w, W_f_w, U_f_w,
                                      PFh, PFl, Wiouh, Wioul, Uiouh, Uioul,
                                      Wfh, Wfl, Ufh, Ufl, counts);

  tree_levels<<<NBLK, 256, 0, stream>>>(
      parent_idx, PFh, PFl, H0h, H0l, Wiouh, Wioul, Uiouh, Uioul,
      Wfh, Wfl, Ufh, Ufl, W_iou_b, W_f_b, h_d, c_d, fc, c_part, HSh, HSl,
      counts, offs, cursor, eidx, barcnt, bargen);
}